// Round 9
// baseline (430.859 us; speedup 1.0000x reference)
//
#include <hip/hip_runtime.h>
#include <stdint.h>

#define NN 100000
#define NE 1600000
#define NR 4
#define NK (NN * NR)      // 400000 (dst,rel) keys
#define FD 128
#define KT 640
#define NQ 1024
#define HIDN 256

#define NB 391            // dst buckets of 256 nodes
#define BSH 8
#define CAPB 8192
#define EPB 2048
#define NBLK1 ((NE + EPB - 1) / EPB)   // 782
#define NT1 (NN / 16)                  // 6250 node-tiles, layer 1
#define NT2 (2 * NQ / 16)              // 128 query-tiles, layer 2

using u16 = unsigned short;
using u32 = unsigned int;
typedef __attribute__((ext_vector_type(8))) __bf16 bf16x8;
typedef __attribute__((ext_vector_type(4))) float f32x4;

__device__ __forceinline__ u16 f2b(float f) {
    u32 u = __builtin_bit_cast(u32, f);
    u32 r = u + 0x7FFFu + ((u >> 16) & 1u);   // round-to-nearest-even
    return (u16)(r >> 16);
}
__device__ __forceinline__ float b2f_lo(u32 v) { return __builtin_bit_cast(float, v << 16); }
__device__ __forceinline__ float b2f_hi(u32 v) { return __builtin_bit_cast(float, v & 0xFFFF0000u); }
__device__ __forceinline__ u32 pack2(float a, float b) {
    return (u32)f2b(a) | ((u32)f2b(b) << 16);
}

// ---------- phase 1: bucket scatter into fixed-capacity bucket-major segments ----------
__global__ __launch_bounds__(256) void bucket_scatter(const int* __restrict__ ei,
                                                      const int* __restrict__ et,
                                                      int* __restrict__ bcnt,
                                                      u32* __restrict__ bpack) {
    __shared__ int hist[NB];
    __shared__ int base[NB];
    int t = threadIdx.x;
    for (int i = t; i < NB; i += 256) hist[i] = 0;
    __syncthreads();
    int e0 = blockIdx.x * EPB;
    int rank[8];
    u32 pk[8];
    int bk[8];
#pragma unroll
    for (int j = 0; j < 8; ++j) {
        int e = e0 + j * 256 + t;
        bk[j] = -1;
        if (e < NE) {
            int src = __builtin_nontemporal_load(ei + e);
            int dst = __builtin_nontemporal_load(ei + NE + e);
            int r   = __builtin_nontemporal_load(et + e);
            bk[j] = dst >> BSH;
            pk[j] = (u32)src | ((u32)r << 17) | ((u32)(dst & 255) << 19);
            rank[j] = atomicAdd(&hist[bk[j]], 1);
        }
    }
    __syncthreads();
    for (int i = t; i < NB; i += 256) {
        int h = hist[i];
        base[i] = h ? atomicAdd(&bcnt[i], h) : 0;
    }
    __syncthreads();
#pragma unroll
    for (int j = 0; j < 8; ++j)
        if (bk[j] >= 0) bpack[(size_t)bk[j] * CAPB + base[bk[j]] + rank[j]] = pk[j];
}

// ---------- exclusive scan of bucket counts ----------
__global__ __launch_bounds__(512) void bucket_scan(const int* __restrict__ bcnt,
                                                   int* __restrict__ bbase,
                                                   int* __restrict__ offs4) {
    __shared__ int sm[512];
    int t = threadIdx.x;
    int v = (t < NB) ? bcnt[t] : 0;
    sm[t] = v;
    __syncthreads();
    for (int o2 = 1; o2 < 512; o2 <<= 1) {
        int n = (t >= o2) ? sm[t - o2] : 0;
        __syncthreads();
        sm[t] += n;
        __syncthreads();
    }
    if (t < NB) bbase[t] = sm[t] - v;
    if (t == 0) offs4[NK] = NE;
}

// ---------- phase 2: per-bucket key sort; also emits offs4 ----------
__global__ __launch_bounds__(256) void key_scatter(const int* __restrict__ bcnt,
                                                   const int* __restrict__ bbase,
                                                   const u32* __restrict__ bpack,
                                                   int* __restrict__ offs4,
                                                   int* __restrict__ spack) {
    __shared__ int hist[1024];
    __shared__ int sm[256];
    int b = blockIdx.x, t = threadIdx.x;
    int cnt = bcnt[b];
    int gbase = bbase[b];
    const u32* seg = bpack + (size_t)b * CAPB;
#pragma unroll
    for (int j = 0; j < 4; ++j) hist[t + j * 256] = 0;
    __syncthreads();
    for (int i = t; i < cnt; i += 256) {
        u32 pk = seg[i];
        atomicAdd(&hist[pk >> 17], 1);
    }
    __syncthreads();
    int t4 = t * 4;
    int h0 = hist[t4], h1 = hist[t4 + 1], h2 = hist[t4 + 2], h3 = hist[t4 + 3];
    int s = h0 + h1 + h2 + h3;
    sm[t] = s;
    __syncthreads();
    for (int o2 = 1; o2 < 256; o2 <<= 1) {
        int n = (t >= o2) ? sm[t - o2] : 0;
        __syncthreads();
        sm[t] += n;
        __syncthreads();
    }
    int e0 = gbase + sm[t] - s;
    int e1 = e0 + h0, e2 = e1 + h1, e3 = e2 + h2;
    int k0 = b << 10;
    if (k0 + t4 + 0 < NK) offs4[k0 + t4 + 0] = e0;
    if (k0 + t4 + 1 < NK) offs4[k0 + t4 + 1] = e1;
    if (k0 + t4 + 2 < NK) offs4[k0 + t4 + 2] = e2;
    if (k0 + t4 + 3 < NK) offs4[k0 + t4 + 3] = e3;
    hist[t4] = e0; hist[t4 + 1] = e1; hist[t4 + 2] = e2; hist[t4 + 3] = e3;
    __syncthreads();
    for (int i = t; i < cnt; i += 256) {
        u32 pk = seg[i];
        int pos = atomicAdd(&hist[pk >> 17], 1);
        spack[pos] = (int)(pk & 0x1FFFFu);
    }
}

// ---------- conversions / weight prep ----------
__global__ __launch_bounds__(256) void cvt_bf16(const float* __restrict__ in,
                                                u16* __restrict__ outp, int n) {
    int i = blockIdx.x * 256 + threadIdx.x;
    int idx = i * 4;
    if (idx + 3 >= n) {
        for (int j = idx; j < n; ++j) outp[j] = f2b(in[j]);
        return;
    }
    float4 v = *(const float4*)(in + idx);
    u32 lo = (u32)f2b(v.x) | ((u32)f2b(v.y) << 16);
    u32 hi = (u32)f2b(v.z) | ((u32)f2b(v.w) << 16);
    *(uint2*)(outp + idx) = make_uint2(lo, hi);
}

__global__ __launch_bounds__(256) void prep_B(const float* __restrict__ Wrel,
                                              const float* __restrict__ Wroot,
                                              u16* __restrict__ Bt) {
    int i = blockIdx.x * 256 + threadIdx.x;
    if (i >= FD * KT) return;
    int k = i % KT;
    int o = i / KT;
    float v = (k < 512) ? Wrel[(size_t)k * FD + o] : Wroot[(size_t)(k - 512) * FD + o];
    Bt[i] = f2b(v);
}

// ---------- fused RGCN layer: gather + normalize + GEMM + bias(+relu), barrier-free ----------
// One wave owns 16 output rows. Two passes over rel pairs {0,1},{2,3}: gather each
// node's per-rel mean into a wave-private LDS tile [16][256] bf16 (XOR-swizzled),
// then 8 K-steps x 8 N-tiles of mfma 16x16x32 against Bt (L2-hot). Root block
// (k=512..639) uses direct global fragment loads (no LDS). No __syncthreads.
__global__ __launch_bounds__(256) void rgcn_fused(const int* __restrict__ offs4,
                                                  const int* __restrict__ spack,
                                                  const u32* __restrict__ fp,     // gather src u32[.][64], row NN = 0
                                                  const u16* __restrict__ rootSrc,
                                                  const u16* __restrict__ Bt,
                                                  const float* __restrict__ bias,
                                                  void* __restrict__ outp,
                                                  int ntiles,
                                                  const int* __restrict__ nest,
                                                  const int* __restrict__ food,
                                                  int qmode) {
    __shared__ u16 ldsAll[4 * 16 * 256];   // 32 KB: 8 KB per wave
    int tid = threadIdx.x, wid = tid >> 6, lane = tid & 63;
    int tile = blockIdx.x * 4 + wid;
    if (tile >= ntiles) return;
    int n0 = tile * 16;
    int lr = lane & 15, hi = lane >> 4;
    char* L = (char*)ldsAll + wid * 8192;

    f32x4 acc[8];
#pragma unroll
    for (int i = 0; i < 8; ++i) acc[i] = (f32x4){0.f, 0.f, 0.f, 0.f};

#pragma unroll
    for (int pass = 0; pass < 2; ++pass) {
        // ---- gather phase: 16 nodes x 2 relations ----
        for (int i = 0; i < 16; ++i) {
            int row = n0 + i;
            int node = qmode ? ((row < NQ) ? nest[row] : food[row - NQ]) : row;
            node = __builtin_amdgcn_readfirstlane(node);
            const int* ob = offs4 + (size_t)node * 4 + pass * 2;
            int s0 = __builtin_amdgcn_readfirstlane(ob[0]);
            int s1 = __builtin_amdgcn_readfirstlane(ob[1]);
            int s2 = __builtin_amdgcn_readfirstlane(ob[2]);
            float a0 = 0, a1 = 0, c0 = 0, c1 = 0;
            // rel even: [s0,s1)
            {
                int last = s1 - 1;
                for (int e = s0; e < s1; e += 8) {
                    int p[8];
                    u32 v[8];
#pragma unroll
                    for (int j = 0; j < 8; ++j) {
                        int ij = e + j;
                        int cl = ij <= last ? ij : last;
                        int pv = spack[cl];
                        p[j] = (ij <= last) ? pv : NN;
                    }
#pragma unroll
                    for (int j = 0; j < 8; ++j) v[j] = fp[(size_t)p[j] * 64 + lane];
#pragma unroll
                    for (int j = 0; j < 8; ++j) { a0 += b2f_lo(v[j]); a1 += b2f_hi(v[j]); }
                }
            }
            // rel odd: [s1,s2)
            {
                int last = s2 - 1;
                for (int e = s1; e < s2; e += 8) {
                    int p[8];
                    u32 v[8];
#pragma unroll
                    for (int j = 0; j < 8; ++j) {
                        int ij = e + j;
                        int cl = ij <= last ? ij : last;
                        int pv = spack[cl];
                        p[j] = (ij <= last) ? pv : NN;
                    }
#pragma unroll
                    for (int j = 0; j < 8; ++j) v[j] = fp[(size_t)p[j] * 64 + lane];
#pragma unroll
                    for (int j = 0; j < 8; ++j) { c0 += b2f_lo(v[j]); c1 += b2f_hi(v[j]); }
                }
            }
            int d0 = s1 - s0, d1 = s2 - s1;
            float f0 = 1.0f / (float)(d0 > 1 ? d0 : 1);
            float f1 = 1.0f / (float)(d1 > 1 ? d1 : 1);
            int swz = (i & 7) << 4;
            *(u32*)(L + i * 512 + ((lane * 4) ^ swz)) = pack2(a0 * f0, a1 * f0);
            *(u32*)(L + i * 512 + ((256 + lane * 4) ^ swz)) = pack2(c0 * f1, c1 * f1);
        }
        // ---- MFMA phase: K = 256 for this pass (compiler inserts lgkmcnt waits) ----
#pragma unroll
        for (int kk = 0; kk < 8; ++kk) {
            bf16x8 af = *reinterpret_cast<const bf16x8*>(
                L + lr * 512 + ((kk * 64 + hi * 16) ^ ((lr & 7) << 4)));
#pragma unroll
            for (int nt = 0; nt < 8; ++nt) {
                int col = nt * 16 + lr;
                bf16x8 bfr = *reinterpret_cast<const bf16x8*>(
                    Bt + (size_t)col * KT + pass * 256 + kk * 32 + hi * 8);
                acc[nt] = __builtin_amdgcn_mfma_f32_16x16x32_bf16(af, bfr, acc[nt], 0, 0, 0);
            }
        }
    }

    // ---- root block: k = 512..639, direct global fragments ----
    {
        int grow = n0 + lr;
        int node = qmode ? ((grow < NQ) ? nest[grow] : food[grow - NQ]) : grow;
        const u16* rp = rootSrc + (size_t)node * FD + hi * 8;
#pragma unroll
        for (int kk = 0; kk < 4; ++kk) {
            bf16x8 af = *reinterpret_cast<const bf16x8*>(rp + kk * 32);
#pragma unroll
            for (int nt = 0; nt < 8; ++nt) {
                int col = nt * 16 + lr;
                bf16x8 bfr = *reinterpret_cast<const bf16x8*>(
                    Bt + (size_t)col * KT + 512 + kk * 32 + hi * 8);
                acc[nt] = __builtin_amdgcn_mfma_f32_16x16x32_bf16(af, bfr, acc[nt], 0, 0, 0);
            }
        }
    }

    // ---- epilogue: D col = lane&15, row = 4*(lane>>4)+reg ----
#pragma unroll
    for (int nt = 0; nt < 8; ++nt) {
        int col = nt * 16 + lr;
        float bv = bias[col];
#pragma unroll
        for (int rg = 0; rg < 4; ++rg) {
            int row = n0 + hi * 4 + rg;
            float v = acc[nt][rg] + bv;
            if (qmode) {
                ((float*)outp)[(size_t)row * FD + col] = v;
            } else {
                ((u16*)outp)[(size_t)row * FD + col] = f2b(fmaxf(v, 0.f));
            }
        }
    }
}

// ---------- final FC ----------
__global__ __launch_bounds__(256) void fc_kernel(const float* __restrict__ h2q,
                                                 const float* __restrict__ Wfc,
                                                 const float* __restrict__ bfc,
                                                 float* __restrict__ out) {
    __shared__ float comb[2 * FD];
    int q = blockIdx.x, t = threadIdx.x;
    if (t < FD) comb[t] = h2q[(size_t)q * FD + t];
    else comb[t] = h2q[(size_t)(NQ + q) * FD + (t - FD)];
    __syncthreads();
    float s = bfc[t];
#pragma unroll 4
    for (int k = 0; k < 2 * FD; ++k) s += comb[k] * Wfc[(size_t)k * HIDN + t];
    out[(size_t)q * HIDN + t] = fmaxf(s, 0.f);
}

extern "C" void kernel_launch(void* const* d_in, const int* in_sizes, int n_in,
                              void* d_out, int out_size, void* d_ws, size_t ws_size,
                              hipStream_t stream) {
    const float* x      = (const float*)d_in[0];
    const int*   ei     = (const int*)d_in[1];
    const int*   et     = (const int*)d_in[2];
    const int*   nest   = (const int*)d_in[3];
    const int*   food   = (const int*)d_in[4];
    const float* Wrel1  = (const float*)d_in[5];
    const float* Wroot1 = (const float*)d_in[6];
    const float* b1     = (const float*)d_in[7];
    const float* Wrel2  = (const float*)d_in[8];
    const float* Wroot2 = (const float*)d_in[9];
    const float* b2     = (const float*)d_in[10];
    const float* Wfc    = (const float*)d_in[11];
    const float* bfc    = (const float*)d_in[12];
    float* out = (float*)d_out;

    char* w = (char*)d_ws;
    size_t off = 0;
    auto take = [&](size_t b) {
        char* p = w + off;
        off += b;
        off = (off + 255) & ~(size_t)255;
        return p;
    };
    int* bcnt   = (int*)take((size_t)NB * 4);
    int* bbase  = (int*)take((size_t)NB * 4);
    int* offs4  = (int*)take(((size_t)NK + 1) * 4);
    u32* bpack  = (u32*)take((size_t)NB * CAPB * 4);
    int* spack  = (int*)take((size_t)NE * 4);
    u16* xh     = (u16*)take((size_t)(NN + 1) * FD * 2);   // row NN = zeros (dummy row)
    u16* h1     = (u16*)take((size_t)(NN + 1) * FD * 2);   // row NN = zeros (dummy row)
    u16* Bt1    = (u16*)take((size_t)FD * KT * 2);
    u16* Bt2    = (u16*)take((size_t)FD * KT * 2);
    float* h2q  = (float*)take((size_t)2 * NQ * FD * 4);

    hipMemsetAsync(bcnt, 0, (size_t)NB * 4, stream);
    hipMemsetAsync(xh + (size_t)NN * FD, 0, FD * 2, stream);   // zero dummy row
    hipMemsetAsync(h1 + (size_t)NN * FD, 0, FD * 2, stream);   // zero dummy row
    cvt_bf16<<<((NN * FD / 4) + 255) / 256, 256, 0, stream>>>(x, xh, NN * FD);
    prep_B<<<(FD * KT + 255) / 256, 256, 0, stream>>>(Wrel1, Wroot1, Bt1);
    prep_B<<<(FD * KT + 255) / 256, 256, 0, stream>>>(Wrel2, Wroot2, Bt2);
    bucket_scatter<<<NBLK1, 256, 0, stream>>>(ei, et, bcnt, bpack);
    bucket_scan<<<1, 512, 0, stream>>>(bcnt, bbase, offs4);
    key_scatter<<<NB, 256, 0, stream>>>(bcnt, bbase, bpack, offs4, spack);

    // layer 1: all nodes, fused gather+GEMM, h1 = relu(...)
    rgcn_fused<<<(NT1 + 3) / 4, 256, 0, stream>>>(offs4, spack, (const u32*)xh, xh,
                                                  Bt1, b1, (void*)h1, NT1,
                                                  nullptr, nullptr, 0);
    // layer 2: 2048 query rows, fused, h2q (f32, no relu)
    rgcn_fused<<<(NT2 + 3) / 4, 256, 0, stream>>>(offs4, spack, (const u32*)h1, h1,
                                                  Bt2, b2, (void*)h2q, NT2,
                                                  nest, food, 1);
    fc_kernel<<<NQ, 256, 0, stream>>>(h2q, Wfc, bfc, out);
}

// Round 10
// 294.135 us; speedup vs baseline: 1.4648x; 1.4648x over previous
//
#include <hip/hip_runtime.h>
#include <stdint.h>

#define NN 100000
#define NE 1600000
#define NR 4
#define NK (NN * NR)      // 400000 (dst,rel) keys
#define FD 128
#define KT 640
#define NQ 1024
#define HIDN 256

#define NB 391            // dst buckets of 256 nodes
#define BSH 8
#define CAPB 8192
#define EPB 2048
#define NBLK1 ((NE + EPB - 1) / EPB)   // 782
#define LROW 1280         // LDS bytes per row (640 bf16)

using u16 = unsigned short;
using u32 = unsigned int;
typedef __attribute__((ext_vector_type(8))) __bf16 bf16x8;
typedef __attribute__((ext_vector_type(4))) float f32x4;

__device__ __forceinline__ u16 f2b(float f) {
    u32 u = __builtin_bit_cast(u32, f);
    u32 r = u + 0x7FFFu + ((u >> 16) & 1u);   // round-to-nearest-even
    return (u16)(r >> 16);
}
__device__ __forceinline__ float b2f_lo(u32 v) { return __builtin_bit_cast(float, v << 16); }
__device__ __forceinline__ float b2f_hi(u32 v) { return __builtin_bit_cast(float, v & 0xFFFF0000u); }
__device__ __forceinline__ u32 pack2(float a, float b) {
    return (u32)f2b(a) | ((u32)f2b(b) << 16);
}

// ---------- phase 1: bucket scatter into fixed-capacity bucket-major segments ----------
__global__ __launch_bounds__(256) void bucket_scatter(const int* __restrict__ ei,
                                                      const int* __restrict__ et,
                                                      int* __restrict__ bcnt,
                                                      u32* __restrict__ bpack) {
    __shared__ int hist[NB];
    __shared__ int base[NB];
    int t = threadIdx.x;
    for (int i = t; i < NB; i += 256) hist[i] = 0;
    __syncthreads();
    int e0 = blockIdx.x * EPB;
    int rank[8];
    u32 pk[8];
    int bk[8];
#pragma unroll
    for (int j = 0; j < 8; ++j) {
        int e = e0 + j * 256 + t;
        bk[j] = -1;
        if (e < NE) {
            int src = __builtin_nontemporal_load(ei + e);
            int dst = __builtin_nontemporal_load(ei + NE + e);
            int r   = __builtin_nontemporal_load(et + e);
            bk[j] = dst >> BSH;
            pk[j] = (u32)src | ((u32)r << 17) | ((u32)(dst & 255) << 19);
            rank[j] = atomicAdd(&hist[bk[j]], 1);
        }
    }
    __syncthreads();
    for (int i = t; i < NB; i += 256) {
        int h = hist[i];
        base[i] = h ? atomicAdd(&bcnt[i], h) : 0;
    }
    __syncthreads();
#pragma unroll
    for (int j = 0; j < 8; ++j)
        if (bk[j] >= 0) bpack[(size_t)bk[j] * CAPB + base[bk[j]] + rank[j]] = pk[j];
}

// ---------- exclusive scan of bucket counts ----------
__global__ __launch_bounds__(512) void bucket_scan(const int* __restrict__ bcnt,
                                                   int* __restrict__ bbase,
                                                   int* __restrict__ offs4) {
    __shared__ int sm[512];
    int t = threadIdx.x;
    int v = (t < NB) ? bcnt[t] : 0;
    sm[t] = v;
    __syncthreads();
    for (int o2 = 1; o2 < 512; o2 <<= 1) {
        int n = (t >= o2) ? sm[t - o2] : 0;
        __syncthreads();
        sm[t] += n;
        __syncthreads();
    }
    if (t < NB) bbase[t] = sm[t] - v;
    if (t == 0) offs4[NK] = NE;
}

// ---------- phase 2: per-bucket key sort; also emits offs4 ----------
__global__ __launch_bounds__(256) void key_scatter(const int* __restrict__ bcnt,
                                                   const int* __restrict__ bbase,
                                                   const u32* __restrict__ bpack,
                                                   int* __restrict__ offs4,
                                                   int* __restrict__ spack) {
    __shared__ int hist[1024];
    __shared__ int sm[256];
    int b = blockIdx.x, t = threadIdx.x;
    int cnt = bcnt[b];
    int gbase = bbase[b];
    const u32* seg = bpack + (size_t)b * CAPB;
#pragma unroll
    for (int j = 0; j < 4; ++j) hist[t + j * 256] = 0;
    __syncthreads();
    for (int i = t; i < cnt; i += 256) {
        u32 pk = seg[i];
        atomicAdd(&hist[pk >> 17], 1);
    }
    __syncthreads();
    int t4 = t * 4;
    int h0 = hist[t4], h1 = hist[t4 + 1], h2 = hist[t4 + 2], h3 = hist[t4 + 3];
    int s = h0 + h1 + h2 + h3;
    sm[t] = s;
    __syncthreads();
    for (int o2 = 1; o2 < 256; o2 <<= 1) {
        int n = (t >= o2) ? sm[t - o2] : 0;
        __syncthreads();
        sm[t] += n;
        __syncthreads();
    }
    int e0 = gbase + sm[t] - s;
    int e1 = e0 + h0, e2 = e1 + h1, e3 = e2 + h2;
    int k0 = b << 10;
    if (k0 + t4 + 0 < NK) offs4[k0 + t4 + 0] = e0;
    if (k0 + t4 + 1 < NK) offs4[k0 + t4 + 1] = e1;
    if (k0 + t4 + 2 < NK) offs4[k0 + t4 + 2] = e2;
    if (k0 + t4 + 3 < NK) offs4[k0 + t4 + 3] = e3;
    hist[t4] = e0; hist[t4 + 1] = e1; hist[t4 + 2] = e2; hist[t4 + 3] = e3;
    __syncthreads();
    for (int i = t; i < cnt; i += 256) {
        u32 pk = seg[i];
        int pos = atomicAdd(&hist[pk >> 17], 1);
        spack[pos] = (int)(pk & 0x1FFFFu);
    }
}

// ---------- conversions / weight prep ----------
__global__ __launch_bounds__(256) void cvt_bf16(const float* __restrict__ in,
                                                u16* __restrict__ outp, int n) {
    int i = blockIdx.x * 256 + threadIdx.x;
    int idx = i * 4;
    if (idx + 3 >= n) {
        for (int j = idx; j < n; ++j) outp[j] = f2b(in[j]);
        return;
    }
    float4 v = *(const float4*)(in + idx);
    u32 lo = (u32)f2b(v.x) | ((u32)f2b(v.y) << 16);
    u32 hi = (u32)f2b(v.z) | ((u32)f2b(v.w) << 16);
    *(uint2*)(outp + idx) = make_uint2(lo, hi);
}

__global__ __launch_bounds__(256) void prep_B(const float* __restrict__ Wrel,
                                              const float* __restrict__ Wroot,
                                              u16* __restrict__ Bt) {
    int i = blockIdx.x * 256 + threadIdx.x;
    if (i >= FD * KT) return;
    int k = i % KT;
    int o = i / KT;
    float v = (k < 512) ? Wrel[(size_t)k * FD + o] : Wroot[(size_t)(k - 512) * FD + o];
    Bt[i] = f2b(v);
}

// ---------- fused RGCN layer, 16-row tile per BLOCK (4 rows per wave) ----------
// Gather phase: each of 4 waves gathers 4 rows (proven agg body: scalar bounds,
// 8-deep ILP, dummy row NN) into block LDS [16][640] bf16, XOR-swizzled.
// One barrier. MFMA phase: each wave computes 2 col-tiles of C[16][128]
// (20 K-steps), B from L2-resident Bt. Epilogue bias(+relu) direct to output.
__global__ __launch_bounds__(256) void rgcn_tile16(const int* __restrict__ offs4,
                                                   const int* __restrict__ spack,
                                                   const u32* __restrict__ fp,   // u32[.][64], row NN = 0
                                                   const u16* __restrict__ Bt,
                                                   const float* __restrict__ bias,
                                                   void* __restrict__ outp,
                                                   const int* __restrict__ nest,
                                                   const int* __restrict__ food,
                                                   int qmode) {
    __shared__ u16 lds_[16 * KT];   // 20 KB
    char* L = (char*)lds_;
    int tid = threadIdx.x, wid = tid >> 6, lane = tid & 63;
    int lr = lane & 15, hi = lane >> 4;
    int n0 = blockIdx.x * 16;

    // ---- gather phase: wave wid owns tile rows wid*4 .. wid*4+3 ----
    for (int rr = 0; rr < 4; ++rr) {
        int i = wid * 4 + rr;
        int row = n0 + i;
        int node = qmode ? ((row < NQ) ? nest[row] : food[row - NQ]) : row;
        node = __builtin_amdgcn_readfirstlane(node);

        const int* ob = offs4 + (size_t)node * 4;
        int o0 = __builtin_amdgcn_readfirstlane(ob[0]);
        int o1 = __builtin_amdgcn_readfirstlane(ob[1]);
        int o2 = __builtin_amdgcn_readfirstlane(ob[2]);
        int o3 = __builtin_amdgcn_readfirstlane(ob[3]);
        int o4 = __builtin_amdgcn_readfirstlane(ob[4]);

        float a00 = 0, a01 = 0, a10 = 0, a11 = 0, a20 = 0, a21 = 0, a30 = 0, a31 = 0;
        int lastIdx = o4 - 1;

        for (int e = o0; e < o4; e += 8) {
            int p[8];
            u32 v[8];
#pragma unroll
            for (int j = 0; j < 8; ++j) {
                int ij = e + j;
                int cl = ij <= lastIdx ? ij : lastIdx;
                int pv = spack[cl];
                p[j] = (ij <= lastIdx) ? pv : NN;   // dummy -> zero row
            }
#pragma unroll
            for (int j = 0; j < 8; ++j) v[j] = fp[(size_t)p[j] * 64 + lane];
#pragma unroll
            for (int j = 0; j < 8; ++j) {
                int ij = e + j;
                float f0 = b2f_lo(v[j]);
                float f1 = b2f_hi(v[j]);
                if (ij < o1)      { a00 += f0; a01 += f1; }
                else if (ij < o2) { a10 += f0; a11 += f1; }
                else if (ij < o3) { a20 += f0; a21 += f1; }
                else              { a30 += f0; a31 += f1; }
            }
        }

        int d0 = o1 - o0, d1 = o2 - o1, d2 = o3 - o2, d3 = o4 - o3;
        float s0 = 1.0f / (float)(d0 > 1 ? d0 : 1);
        float s1 = 1.0f / (float)(d1 > 1 ? d1 : 1);
        float s2 = 1.0f / (float)(d2 > 1 ? d2 : 1);
        float s3 = 1.0f / (float)(d3 > 1 ? d3 : 1);

        int swz = (i & 7) << 4;
        char* Lr = L + (size_t)i * LROW;
        *(u32*)(Lr + ((0   + lane * 4) ^ swz)) = pack2(a00 * s0, a01 * s0);
        *(u32*)(Lr + ((256 + lane * 4) ^ swz)) = pack2(a10 * s1, a11 * s1);
        *(u32*)(Lr + ((512 + lane * 4) ^ swz)) = pack2(a20 * s2, a21 * s2);
        *(u32*)(Lr + ((768 + lane * 4) ^ swz)) = pack2(a30 * s3, a31 * s3);
        *(u32*)(Lr + ((1024 + lane * 4) ^ swz)) = fp[(size_t)node * 64 + lane];  // root
    }
    __syncthreads();

    // ---- MFMA phase: wave wid owns col-tiles {2*wid, 2*wid+1} ----
    f32x4 acc[2];
    acc[0] = (f32x4){0.f, 0.f, 0.f, 0.f};
    acc[1] = (f32x4){0.f, 0.f, 0.f, 0.f};
#pragma unroll
    for (int ks = 0; ks < 20; ++ks) {
        bf16x8 af = *reinterpret_cast<const bf16x8*>(
            L + (size_t)lr * LROW + ((ks * 64 + hi * 16) ^ ((lr & 7) << 4)));
#pragma unroll
        for (int n = 0; n < 2; ++n) {
            int col = (wid * 2 + n) * 16 + lr;
            bf16x8 bfr = *reinterpret_cast<const bf16x8*>(
                Bt + (size_t)col * KT + ks * 32 + hi * 8);
            acc[n] = __builtin_amdgcn_mfma_f32_16x16x32_bf16(af, bfr, acc[n], 0, 0, 0);
        }
    }

    // ---- epilogue: D col = lane&15, row = 4*(lane>>4)+reg ----
#pragma unroll
    for (int n = 0; n < 2; ++n) {
        int col = (wid * 2 + n) * 16 + lr;
        float bv = bias[col];
#pragma unroll
        for (int rg = 0; rg < 4; ++rg) {
            int row = n0 + hi * 4 + rg;
            float v = acc[n][rg] + bv;
            if (qmode) ((float*)outp)[(size_t)row * FD + col] = v;
            else       ((u16*)outp)[(size_t)row * FD + col] = f2b(fmaxf(v, 0.f));
        }
    }
}

// ---------- final FC ----------
__global__ __launch_bounds__(256) void fc_kernel(const float* __restrict__ h2q,
                                                 const float* __restrict__ Wfc,
                                                 const float* __restrict__ bfc,
                                                 float* __restrict__ out) {
    __shared__ float comb[2 * FD];
    int q = blockIdx.x, t = threadIdx.x;
    if (t < FD) comb[t] = h2q[(size_t)q * FD + t];
    else comb[t] = h2q[(size_t)(NQ + q) * FD + (t - FD)];
    __syncthreads();
    float s = bfc[t];
#pragma unroll 4
    for (int k = 0; k < 2 * FD; ++k) s += comb[k] * Wfc[(size_t)k * HIDN + t];
    out[(size_t)q * HIDN + t] = fmaxf(s, 0.f);
}

extern "C" void kernel_launch(void* const* d_in, const int* in_sizes, int n_in,
                              void* d_out, int out_size, void* d_ws, size_t ws_size,
                              hipStream_t stream) {
    const float* x      = (const float*)d_in[0];
    const int*   ei     = (const int*)d_in[1];
    const int*   et     = (const int*)d_in[2];
    const int*   nest   = (const int*)d_in[3];
    const int*   food   = (const int*)d_in[4];
    const float* Wrel1  = (const float*)d_in[5];
    const float* Wroot1 = (const float*)d_in[6];
    const float* b1     = (const float*)d_in[7];
    const float* Wrel2  = (const float*)d_in[8];
    const float* Wroot2 = (const float*)d_in[9];
    const float* b2     = (const float*)d_in[10];
    const float* Wfc    = (const float*)d_in[11];
    const float* bfc    = (const float*)d_in[12];
    float* out = (float*)d_out;

    char* w = (char*)d_ws;
    size_t off = 0;
    auto take = [&](size_t b) {
        char* p = w + off;
        off += b;
        off = (off + 255) & ~(size_t)255;
        return p;
    };
    int* bcnt   = (int*)take((size_t)NB * 4);
    int* bbase  = (int*)take((size_t)NB * 4);
    int* offs4  = (int*)take(((size_t)NK + 1) * 4);
    u32* bpack  = (u32*)take((size_t)NB * CAPB * 4);
    int* spack  = (int*)take((size_t)NE * 4);
    u16* xh     = (u16*)take((size_t)(NN + 16) * FD * 2);   // row NN.. = zeros (dummy + tile pad)
    u16* h1     = (u16*)take((size_t)(NN + 16) * FD * 2);   // row NN.. = zeros
    u16* Bt1    = (u16*)take((size_t)FD * KT * 2);
    u16* Bt2    = (u16*)take((size_t)FD * KT * 2);
    float* h2q  = (float*)take((size_t)2 * NQ * FD * 4);

    hipMemsetAsync(bcnt, 0, (size_t)NB * 4, stream);
    hipMemsetAsync(xh + (size_t)NN * FD, 0, (size_t)16 * FD * 2, stream);
    hipMemsetAsync(h1 + (size_t)NN * FD, 0, (size_t)16 * FD * 2, stream);
    cvt_bf16<<<((NN * FD / 4) + 255) / 256, 256, 0, stream>>>(x, xh, NN * FD);
    prep_B<<<(FD * KT + 255) / 256, 256, 0, stream>>>(Wrel1, Wroot1, Bt1);
    prep_B<<<(FD * KT + 255) / 256, 256, 0, stream>>>(Wrel2, Wroot2, Bt2);
    bucket_scatter<<<NBLK1, 256, 0, stream>>>(ei, et, bcnt, bpack);
    bucket_scan<<<1, 512, 0, stream>>>(bcnt, bbase, offs4);
    key_scatter<<<NB, 256, 0, stream>>>(bcnt, bbase, bpack, offs4, spack);

    // layer 1: 6250 blocks x 16 rows, fused gather+GEMM -> h1 = relu(...)
    rgcn_tile16<<<NN / 16, 256, 0, stream>>>(offs4, spack, (const u32*)xh, Bt1, b1,
                                             (void*)h1, nullptr, nullptr, 0);
    // layer 2: 128 blocks x 16 query rows -> h2q (f32, no relu)
    rgcn_tile16<<<(2 * NQ) / 16, 256, 0, stream>>>(offs4, spack, (const u32*)h1, Bt2, b2,
                                                   (void*)h2q, nest, food, 1);
    fc_kernel<<<NQ, 256, 0, stream>>>(h2q, Wfc, bfc, out);
}

// Round 11
// 256.497 us; speedup vs baseline: 1.6798x; 1.1467x over previous
//
#include <hip/hip_runtime.h>
#include <stdint.h>

#define NN 100000
#define NE 1600000
#define NR 4
#define NK (NN * NR)
#define FD 128
#define KA 512            // A matrix cols (rel blocks only; root handled separately)
#define KT 640
#define NQ 1024
#define HIDN 256

#define NB 391            // dst buckets of 256 nodes
#define BSH 8
#define CAPB 8192         // per-bucket capacity (edges; avg 4096 + pad <= ~6200)
#define EPB 2048
#define NBLK1 ((NE + EPB - 1) / EPB)   // 782
#define MPAD 100096                    // NN rounded up to 128

using u16 = unsigned short;
using u32 = unsigned int;
typedef __attribute__((ext_vector_type(8))) __bf16 bf16x8;
typedef __attribute__((ext_vector_type(4))) float f32x4;

__device__ __forceinline__ u16 f2b(float f) {
    u32 u = __builtin_bit_cast(u32, f);
    u32 r = u + 0x7FFFu + ((u >> 16) & 1u);   // round-to-nearest-even
    return (u16)(r >> 16);
}
__device__ __forceinline__ float b2f_lo(u32 v) { return __builtin_bit_cast(float, v << 16); }
__device__ __forceinline__ float b2f_hi(u32 v) { return __builtin_bit_cast(float, v & 0xFFFF0000u); }
__device__ __forceinline__ u32 pack2(float a, float b) {
    return (u32)f2b(a) | ((u32)f2b(b) << 16);
}
// async global->LDS, 16B per lane
__device__ __forceinline__ void gload_lds16(const void* g, void* l) {
    __builtin_amdgcn_global_load_lds((const __attribute__((address_space(1))) u32*)g,
                                     (__attribute__((address_space(3))) u32*)l, 16, 0, 0);
}

// ---------- phase 1: bucket scatter into fixed-capacity bucket-major segments ----------
__global__ __launch_bounds__(256) void bucket_scatter(const int* __restrict__ ei,
                                                      const int* __restrict__ et,
                                                      int* __restrict__ bcnt,
                                                      u32* __restrict__ bpack) {
    __shared__ int hist[NB];
    __shared__ int base[NB];
    int t = threadIdx.x;
    for (int i = t; i < NB; i += 256) hist[i] = 0;
    __syncthreads();
    int e0 = blockIdx.x * EPB;
    int rank[8];
    u32 pk[8];
    int bk[8];
#pragma unroll
    for (int j = 0; j < 8; ++j) {
        int e = e0 + j * 256 + t;
        bk[j] = -1;
        if (e < NE) {
            int src = __builtin_nontemporal_load(ei + e);
            int dst = __builtin_nontemporal_load(ei + NE + e);
            int r   = __builtin_nontemporal_load(et + e);
            bk[j] = dst >> BSH;
            pk[j] = (u32)src | ((u32)r << 17) | ((u32)(dst & 255) << 19);
            rank[j] = atomicAdd(&hist[bk[j]], 1);
        }
    }
    __syncthreads();
    for (int i = t; i < NB; i += 256) {
        int h = hist[i];
        base[i] = h ? atomicAdd(&bcnt[i], h) : 0;
    }
    __syncthreads();
#pragma unroll
    for (int j = 0; j < 8; ++j)
        if (bk[j] >= 0) bpack[(size_t)bk[j] * CAPB + base[bk[j]] + rank[j]] = pk[j];
}

// ---------- phase 2: per-bucket key sort with PER-NODE PADDING to x8 ----------
// Emits offs6[node*6] = {start, o1, o2, o3, end_exact, padded_end} (spack indices,
// bucket-major: bucket b occupies [b*CAPB, b*CAPB + padded_total)). Pad slots = NN.
__global__ __launch_bounds__(256) void key_scatter(const int* __restrict__ bcnt,
                                                   const u32* __restrict__ bpack,
                                                   int* __restrict__ offs6,
                                                   int* __restrict__ spack) {
    __shared__ int hist[1024];
    __shared__ int sm[256];
    int b = blockIdx.x, t = threadIdx.x;
    int cnt = bcnt[b];
    const u32* seg = bpack + (size_t)b * CAPB;
#pragma unroll
    for (int j = 0; j < 4; ++j) hist[t + j * 256] = 0;
    __syncthreads();
    for (int i = t; i < cnt; i += 256) atomicAdd(&hist[seg[i] >> 17], 1);
    __syncthreads();
    int t4 = t * 4;
    int h0 = hist[t4], h1 = hist[t4 + 1], h2 = hist[t4 + 2], h3 = hist[t4 + 3];
    int s = h0 + h1 + h2 + h3;
    int sp = (s + 7) & ~7;            // node range padded to multiple of 8
    sm[t] = sp;
    __syncthreads();
    for (int o2 = 1; o2 < 256; o2 <<= 1) {
        int n = (t >= o2) ? sm[t - o2] : 0;
        __syncthreads();
        sm[t] += n;
        __syncthreads();
    }
    int bas = b * CAPB + sm[t] - sp;
    int e0 = bas, e1 = e0 + h0, e2 = e1 + h1, e3 = e2 + h2, e4 = e3 + h3, eL = bas + sp;
    int node = (b << 8) + t;
    if (node < NN) {
        int* o = offs6 + (size_t)node * 6;
        o[0] = e0; o[1] = e1; o[2] = e2; o[3] = e3; o[4] = e4; o[5] = eL;
    }
    hist[t4] = e0; hist[t4 + 1] = e1; hist[t4 + 2] = e2; hist[t4 + 3] = e3;
    for (int i = e4; i < eL; ++i) spack[i] = NN;   // pad -> dummy zero row
    __syncthreads();
    for (int i = t; i < cnt; i += 256) {
        u32 pk = seg[i];
        int pos = atomicAdd(&hist[pk >> 17], 1);
        spack[pos] = (int)(pk & 0x1FFFFu);
    }
}

// ---------- conversions / weight prep ----------
__global__ __launch_bounds__(256) void cvt_bf16(const float* __restrict__ in,
                                                u16* __restrict__ outp, int n) {
    int i = blockIdx.x * 256 + threadIdx.x;
    int idx = i * 4;
    if (idx + 3 >= n) {
        for (int j = idx; j < n; ++j) outp[j] = f2b(in[j]);
        return;
    }
    float4 v = *(const float4*)(in + idx);
    u32 lo = (u32)f2b(v.x) | ((u32)f2b(v.y) << 16);
    u32 hi = (u32)f2b(v.z) | ((u32)f2b(v.w) << 16);
    *(uint2*)(outp + idx) = make_uint2(lo, hi);
}

__global__ __launch_bounds__(256) void prep_B(const float* __restrict__ Wrel,
                                              const float* __restrict__ Wroot,
                                              u16* __restrict__ Bt) {
    int i = blockIdx.x * 256 + threadIdx.x;
    if (i >= FD * KT) return;
    int k = i % KT;
    int o = i / KT;
    float v = (k < 512) ? Wrel[(size_t)k * FD + o] : Wroot[(size_t)(k - 512) * FD + o];
    Bt[i] = f2b(v);
}

// ---------- aggregation: one wave per row, padded CSR, all-scalar edge stream ----------
// Edge indices come from SGPRs (readfirstlane) -> feature loads are
// global_load_dword with SGPR base + constant lane offset; per-edge VALU is
// just 2 unpack + 2 add. No clamps: pad entries point at zero row NN and the
// scalar classify drops them into the rel-3 accumulator (+0.0).
__global__ __launch_bounds__(256) void agg_kernel(const int* __restrict__ offs6,
                                                  const int* __restrict__ spack,
                                                  const u32* __restrict__ fp,   // u32[.][64], row NN = 0
                                                  u16* __restrict__ Aout,
                                                  int rows,
                                                  const int* __restrict__ nest,
                                                  const int* __restrict__ food,
                                                  int qmode,
                                                  int* __restrict__ qnodes) {
    int wid = threadIdx.x >> 6, lane = threadIdx.x & 63;
    int row = blockIdx.x * 4 + wid;
    if (row >= rows) return;
    int node;
    if (qmode) node = (row < NQ) ? nest[row] : food[row - NQ];
    else node = row;
    node = __builtin_amdgcn_readfirstlane(node);
    if (qmode && lane == 0) qnodes[row] = node;

    const int* ob = offs6 + (size_t)node * 6;
    int o0 = __builtin_amdgcn_readfirstlane(ob[0]);
    int o1 = __builtin_amdgcn_readfirstlane(ob[1]);
    int o2 = __builtin_amdgcn_readfirstlane(ob[2]);
    int o3 = __builtin_amdgcn_readfirstlane(ob[3]);
    int o4 = __builtin_amdgcn_readfirstlane(ob[4]);   // exact end of rel 3
    int oL = __builtin_amdgcn_readfirstlane(ob[5]);   // padded end (multiple of 8)

    float a00 = 0, a01 = 0, a10 = 0, a11 = 0, a20 = 0, a21 = 0, a30 = 0, a31 = 0;

    for (int e = o0; e < oL; e += 8) {
        int p[8];
        u32 v[8];
#pragma unroll
        for (int j = 0; j < 8; ++j)
            p[j] = __builtin_amdgcn_readfirstlane(spack[e + j]);   // uniform, contiguous
#pragma unroll
        for (int j = 0; j < 8; ++j) v[j] = fp[(size_t)p[j] * 64 + lane];
#pragma unroll
        for (int j = 0; j < 8; ++j) {
            int ij = e + j;                    // scalar
            float f0 = b2f_lo(v[j]);
            float f1 = b2f_hi(v[j]);
            if (ij < o1)      { a00 += f0; a01 += f1; }
            else if (ij < o2) { a10 += f0; a11 += f1; }
            else if (ij < o3) { a20 += f0; a21 += f1; }
            else              { a30 += f0; a31 += f1; }   // pads add 0.0 here
        }
    }

    int d0 = o1 - o0, d1 = o2 - o1, d2 = o3 - o2, d3 = o4 - o3;
    float s0 = 1.0f / (float)(d0 > 1 ? d0 : 1);
    float s1 = 1.0f / (float)(d1 > 1 ? d1 : 1);
    float s2 = 1.0f / (float)(d2 > 1 ? d2 : 1);
    float s3 = 1.0f / (float)(d3 > 1 ? d3 : 1);
    u16* Ao = Aout + (size_t)row * KA + lane * 2;
    *(u32*)(Ao + 0)   = pack2(a00 * s0, a01 * s0);
    *(u32*)(Ao + 128) = pack2(a10 * s1, a11 * s1);
    *(u32*)(Ao + 256) = pack2(a20 * s2, a21 * s2);
    *(u32*)(Ao + 384) = pack2(a30 * s3, a31 * s3);
}

// ---------- GEMM: LDS-staged via global_load_lds (m97 structure, round-8 proven) ----------
__global__ __launch_bounds__(256) void gemm_lds(const u16* __restrict__ A,
                                                const u16* __restrict__ rootSrc,
                                                const int* __restrict__ rootIdx,
                                                const u16* __restrict__ Bt,
                                                const float* __restrict__ bias,
                                                void* __restrict__ Cout,
                                                int M, int relu, int outBf16) {
    __shared__ u16 As[8192];   // 16 KB: [128][64] bf16, swizzled content
    char* lds = (char*)As;
    int tid = threadIdx.x;
    int wid = tid >> 6, lane = tid & 63;
    int wm = wid >> 1, wn = wid & 1;
    int lr = lane & 15, hi = lane >> 4;
    int row0 = blockIdx.x * 128;

    f32x4 acc[4][4];
#pragma unroll
    for (int i = 0; i < 4; ++i)
#pragma unroll
        for (int j = 0; j < 4; ++j) acc[i][j] = (f32x4){0.f, 0.f, 0.f, 0.f};

    int srow = wid * 8 + (lane >> 3);
    int sgl  = (lane & 7);

    for (int t = 0; t < 10; ++t) {
#pragma unroll
        for (int i = 0; i < 4; ++i) {
            int r = i * 32 + srow;
            int sg = sgl ^ (r & 7);
            int gr = row0 + r;
            const u16* src;
            if (t < 8) {
                src = A + (size_t)gr * KA + t * 64 + sg * 8;
            } else {
                int idx = rootIdx ? rootIdx[gr] : gr;
                src = rootSrc + (size_t)idx * FD + (t - 8) * 64 + sg * 8;
            }
            gload_lds16(src, lds + i * 4096 + wid * 1024);
        }
        bf16x8 bfr[2][4];
#pragma unroll
        for (int kk = 0; kk < 2; ++kk)
#pragma unroll
            for (int ni = 0; ni < 4; ++ni) {
                int col = wn * 64 + ni * 16 + lr;
                bfr[kk][ni] = *reinterpret_cast<const bf16x8*>(
                    Bt + (size_t)col * KT + t * 64 + kk * 32 + hi * 8);
            }
        __syncthreads();
#pragma unroll
        for (int kk = 0; kk < 2; ++kk) {
            bf16x8 afr[4];
#pragma unroll
            for (int mi = 0; mi < 4; ++mi) {
                int r = wm * 64 + mi * 16 + lr;
                int sp = (kk * 4 + hi) ^ (r & 7);
                afr[mi] = *reinterpret_cast<const bf16x8*>(lds + r * 128 + sp * 16);
            }
#pragma unroll
            for (int mi = 0; mi < 4; ++mi)
#pragma unroll
                for (int ni = 0; ni < 4; ++ni)
                    acc[mi][ni] = __builtin_amdgcn_mfma_f32_16x16x32_bf16(afr[mi], bfr[kk][ni], acc[mi][ni], 0, 0, 0);
        }
        __syncthreads();
    }

#pragma unroll
    for (int mi = 0; mi < 4; ++mi) {
#pragma unroll
        for (int ni = 0; ni < 4; ++ni) {
            int col = wn * 64 + ni * 16 + lr;
            float bv = bias[col];
#pragma unroll
            for (int rg = 0; rg < 4; ++rg) {
                int row = row0 + wm * 64 + mi * 16 + hi * 4 + rg;
                if (row < M) {
                    float v = acc[mi][ni][rg] + bv;
                    if (relu) v = fmaxf(v, 0.f);
                    if (outBf16) ((u16*)Cout)[(size_t)row * FD + col] = f2b(v);
                    else ((float*)Cout)[(size_t)row * FD + col] = v;
                }
            }
        }
    }
}

// ---------- final FC ----------
__global__ __launch_bounds__(256) void fc_kernel(const float* __restrict__ h2q,
                                                 const float* __restrict__ Wfc,
                                                 const float* __restrict__ bfc,
                                                 float* __restrict__ out) {
    __shared__ float comb[2 * FD];
    int q = blockIdx.x, t = threadIdx.x;
    if (t < FD) comb[t] = h2q[(size_t)q * FD + t];
    else comb[t] = h2q[(size_t)(NQ + q) * FD + (t - FD)];
    __syncthreads();
    float s = bfc[t];
#pragma unroll 4
    for (int k = 0; k < 2 * FD; ++k) s += comb[k] * Wfc[(size_t)k * HIDN + t];
    out[(size_t)q * HIDN + t] = fmaxf(s, 0.f);
}

extern "C" void kernel_launch(void* const* d_in, const int* in_sizes, int n_in,
                              void* d_out, int out_size, void* d_ws, size_t ws_size,
                              hipStream_t stream) {
    const float* x      = (const float*)d_in[0];
    const int*   ei     = (const int*)d_in[1];
    const int*   et     = (const int*)d_in[2];
    const int*   nest   = (const int*)d_in[3];
    const int*   food   = (const int*)d_in[4];
    const float* Wrel1  = (const float*)d_in[5];
    const float* Wroot1 = (const float*)d_in[6];
    const float* b1     = (const float*)d_in[7];
    const float* Wrel2  = (const float*)d_in[8];
    const float* Wroot2 = (const float*)d_in[9];
    const float* b2     = (const float*)d_in[10];
    const float* Wfc    = (const float*)d_in[11];
    const float* bfc    = (const float*)d_in[12];
    float* out = (float*)d_out;

    char* w = (char*)d_ws;
    size_t off = 0;
    auto take = [&](size_t b) {
        char* p = w + off;
        off += b;
        off = (off + 255) & ~(size_t)255;
        return p;
    };
    int* bcnt   = (int*)take((size_t)NB * 4);
    int* offs6  = (int*)take((size_t)NN * 6 * 4);
    u32* bpack  = (u32*)take((size_t)NB * CAPB * 4);
    int* spack  = (int*)take((size_t)NB * CAPB * 4);
    int* qnodes = (int*)take((size_t)2 * NQ * 4);
    u16* xh     = (u16*)take((size_t)MPAD * FD * 2);   // row NN = zeros (dummy row)
    u16* h1     = (u16*)take((size_t)MPAD * FD * 2);   // row NN = zeros (dummy row)
    u16* Bt1    = (u16*)take((size_t)FD * KT * 2);
    u16* Bt2    = (u16*)take((size_t)FD * KT * 2);
    u16* A1     = (u16*)take((size_t)MPAD * KA * 2);
    u16* A2     = (u16*)take((size_t)2 * NQ * KA * 2);
    float* h2q  = (float*)take((size_t)2 * NQ * FD * 4);

    hipMemsetAsync(bcnt, 0, (size_t)NB * 4, stream);
    hipMemsetAsync(xh + (size_t)NN * FD, 0, FD * 2, stream);   // zero dummy row
    hipMemsetAsync(h1 + (size_t)NN * FD, 0, FD * 2, stream);   // zero dummy row
    cvt_bf16<<<((NN * FD / 4) + 255) / 256, 256, 0, stream>>>(x, xh, NN * FD);
    prep_B<<<(FD * KT + 255) / 256, 256, 0, stream>>>(Wrel1, Wroot1, Bt1);
    prep_B<<<(FD * KT + 255) / 256, 256, 0, stream>>>(Wrel2, Wroot2, Bt2);
    bucket_scatter<<<NBLK1, 256, 0, stream>>>(ei, et, bcnt, bpack);
    key_scatter<<<NB, 256, 0, stream>>>(bcnt, bpack, offs6, spack);

    agg_kernel<<<(NN + 3) / 4, 256, 0, stream>>>(offs6, spack, (const u32*)xh, A1,
                                                 NN, nullptr, nullptr, 0, nullptr);
    gemm_lds<<<MPAD / 128, 256, 0, stream>>>(A1, xh, nullptr, Bt1, b1,
                                             (void*)h1, NN, 1, 1);

    agg_kernel<<<(2 * NQ + 3) / 4, 256, 0, stream>>>(offs6, spack, (const u32*)h1, A2,
                                                     2 * NQ, nest, food, 1, qnodes);
    gemm_lds<<<(2 * NQ) / 128, 256, 0, stream>>>(A2, h1, qnodes, Bt2, b2,
                                                 (void*)h2q, 2 * NQ, 0, 0);
    fc_kernel<<<NQ, 256, 0, stream>>>(h2q, Wfc, bfc, out);
}